// Round 1
// baseline (9166.043 us; speedup 1.0000x reference)
//
#include <hip/hip_runtime.h>
#include <hip/hip_cooperative_groups.h>

namespace cg = cooperative_groups;

#define NN    50000
#define RR    4
#define DDEP  5
#define NIN   17400
#define BB    2
#define TT    50
#define EREC  2000000
#define EIN   500000
#define RNN   (RR*NN)   // 200000

struct SP {
  const float* x; const float* rec_w; const float* in_w; const float* bkg;
  const float* v_th; const float* e_l; const float* v_reset; const float* g;
  const float* t_ref; const float* asc_amps; const float* param_k;
  const float* decay; const float* cf; const float* syn_decay; const float* psc_init;
  const float* vscale; const float* voff;
  const int* rec_rows; const int* rec_cols; const int* in_rows; const int* in_cols;
  const int* rest;
  float* out_z; float* out_v;
  float* cur;        // ws: [BB][RNN]
  float* z_hist;     // ws: [BB][DDEP][NN] circular, slot = t % DDEP
  int*   spike_cnt;  // ws: [TT]
};

__global__ __launch_bounds__(256, 2) void snn_all(SP p) {
  cg::grid_group grid = cg::this_grid();
  const int tid = blockIdx.x * blockDim.x + threadIdx.x;
  const int nth = gridDim.x * blockDim.x;

  const bool owner = tid < BB * NN;
  int b = 0, n = 0;
  float sd[RR], pi[RR], bkgv[RR], psc_rise[RR], psc[RR];
  float v = 0.f, refr = 0.f, a1 = 0.f, a2 = 0.f, my_z = 0.f;
  float dcy = 0.f, cfac = 0.f, trf = 0.f, amp1 = 0.f, amp2 = 0.f;
  float ad1 = 0.f, ad2 = 0.f, vth = 0.f, invn = 0.f, leak = 0.f;
  float vrst = 0.f, vsc = 0.f, vof = 0.f;
  #pragma unroll
  for (int r = 0; r < RR; ++r) { sd[r]=0.f; pi[r]=0.f; bkgv[r]=0.f; psc_rise[r]=0.f; psc[r]=0.f; }

  if (owner) {
    b = (tid >= NN) ? 1 : 0;
    n = tid - b * NN;
    #pragma unroll
    for (int r = 0; r < RR; ++r) {
      sd[r]   = p.syn_decay[n*RR + r];
      pi[r]   = p.psc_init[n*RR + r];
      bkgv[r] = p.bkg[n*RR + r];
    }
    vth  = p.v_th[n];
    float el = p.e_l[n];
    invn = 1.0f / (vth - el);
    leak = p.g[n] * el;
    vrst = p.v_reset[n];
    v    = vrst;                       // v0 = broadcast(v_reset)
    dcy  = p.decay[n];
    cfac = p.cf[n];
    trf  = p.t_ref[n];
    amp1 = p.asc_amps[2*n+0];
    amp2 = p.asc_amps[2*n+1];
    ad1  = expf(-p.param_k[2*n+0]);    // asc_decay = exp(-DT*param_k), DT=1
    ad2  = expf(-p.param_k[2*n+1]);
    vsc  = p.vscale[n];
    vof  = p.voff[n];
  }
  float* curb = p.cur    + (size_t)b * RNN;
  float* zh_b = p.z_hist + (size_t)b * (DDEP * NN);

  for (int t = 0; t < TT; ++t) {
    // ================= Phase A: scatter into cur =================
    // recurrent edges, gated by spike counts of the 5 relevant history steps
    unsigned actmask = 0u;           // bit d set -> history step t-1-d had spikes
    #pragma unroll
    for (int d = 0; d < DDEP; ++d) {
      int ts = t - 1 - d;
      if (ts >= 0 && p.spike_cnt[ts] > 0) actmask |= (1u << d);
    }
    if (actmask) {
      for (int e = tid; e < EREC; e += nth) {
        int col = p.rec_cols[e];           // col = d*NN + n_src
        int d = col / NN;                  // 0..4 (magic-mul)
        if (!((actmask >> d) & 1u)) continue;
        int ts   = t - 1 - d;              // >= 0 guaranteed by actmask
        int slot = ts % DDEP;
        int nsrc = col - d * NN;
        float z0 = p.z_hist[slot*NN + nsrc];
        float z1 = p.z_hist[DDEP*NN + slot*NN + nsrc];
        if (z0 == 0.f && z1 == 0.f) continue;
        float w  = p.rec_w[e];
        int row  = p.rec_rows[e];
        if (z0 != 0.f) atomicAdd(&p.cur[row],       w);
        if (z1 != 0.f) atomicAdd(&p.cur[RNN + row], w);
      }
    }
    // input edges (always)
    {
      const float* x0 = p.x + (size_t)t * NIN;                    // b=0: x[0][t][:]
      const float* x1 = p.x + (size_t)TT * NIN + (size_t)t * NIN; // b=1
      for (int e = tid; e < EIN; e += nth) {
        int row = p.in_rows[e];
        int cl  = p.in_cols[e];
        float w = p.in_w[e];
        atomicAdd(&p.cur[row],       x0[cl] * w);
        atomicAdd(&p.cur[RNN + row], x1[cl] * w);
      }
    }
    grid.sync();

    // ================= Phase B: neuron update =================
    if (owner) {
      float restf = (float)p.rest[t*BB + b] * 0.1f;
      float rin[RR];
      #pragma unroll
      for (int r = 0; r < RR; ++r) {
        float c = curb[n*RR + r];
        curb[n*RR + r] = 0.f;              // clear for next step's scatter
        rin[r] = c + bkgv[r] * restf;
      }
      float prev_z = my_z;                 // z_buf[:,0] = our own z from step t-1
      float input_current = psc[0] + psc[1] + psc[2] + psc[3];   // OLD psc
      float new_v = dcy * v + cfac * (input_current + a1 + a2 + leak)
                    + prev_z * (vrst - vth);
      #pragma unroll
      for (int r = 0; r < RR; ++r) {       // new_psc uses OLD psc_rise
        float npsc = psc[r] * sd[r] + sd[r] * psc_rise[r];
        psc_rise[r] = sd[r] * psc_rise[r] + rin[r] * pi[r];
        psc[r] = npsc;
      }
      refr = fmaxf(refr + prev_z * trf - 1.0f, 0.f);
      a1 = ad1 * a1 + prev_z * amp1;
      a2 = ad2 * a2 + prev_z * amp2;
      v = new_v;
      float v_scaled = (new_v - vth) * invn;
      float z = (v_scaled > 0.f) ? 1.f : 0.f;
      if (refr > 0.f) z = 0.f;
      my_z = z;
      zh_b[(t % DDEP)*NN + n] = z;
      size_t oidx = (size_t)b * (TT*NN) + (size_t)t * NN + n;
      p.out_z[oidx] = z;
      p.out_v[oidx] = new_v * vsc + vof;
      unsigned long long m = __ballot(z != 0.f);
      if ((threadIdx.x & 63) == 0 && m != 0ull)
        atomicAdd(&p.spike_cnt[t], (int)__popcll(m));
    }
    grid.sync();
  }
}

extern "C" void kernel_launch(void* const* d_in, const int* in_sizes, int n_in,
                              void* d_out, int out_size, void* d_ws, size_t ws_size,
                              hipStream_t stream) {
  SP p;
  p.x        = (const float*)d_in[0];
  p.rec_w    = (const float*)d_in[1];
  p.in_w     = (const float*)d_in[2];
  p.bkg      = (const float*)d_in[3];
  p.v_th     = (const float*)d_in[4];
  p.e_l      = (const float*)d_in[5];
  p.v_reset  = (const float*)d_in[6];
  p.g        = (const float*)d_in[7];
  p.t_ref    = (const float*)d_in[8];
  p.asc_amps = (const float*)d_in[9];
  p.param_k  = (const float*)d_in[10];
  p.decay    = (const float*)d_in[11];
  p.cf       = (const float*)d_in[12];
  p.syn_decay= (const float*)d_in[13];
  p.psc_init = (const float*)d_in[14];
  p.vscale   = (const float*)d_in[15];
  p.voff     = (const float*)d_in[16];
  p.rec_rows = (const int*)d_in[17];
  p.rec_cols = (const int*)d_in[18];
  p.in_rows  = (const int*)d_in[19];
  p.in_cols  = (const int*)d_in[20];
  p.rest     = (const int*)d_in[21];
  p.out_z = (float*)d_out;
  p.out_v = (float*)d_out + (size_t)BB * TT * NN;

  size_t curBytes = sizeof(float) * (size_t)BB * RNN;      // 1.6 MB
  size_t zhBytes  = sizeof(float) * (size_t)BB * DDEP * NN; // 2.0 MB
  char* ws = (char*)d_ws;
  p.cur       = (float*)ws;
  p.z_hist    = (float*)(ws + curBytes);
  p.spike_cnt = (int*)(ws + curBytes + zhBytes);

  hipMemsetAsync(p.cur, 0, curBytes, stream);
  hipMemsetAsync(p.spike_cnt, 0, sizeof(int) * TT, stream);

  void* args[] = { (void*)&p };
  hipLaunchCooperativeKernel(reinterpret_cast<const void*>(&snn_all),
                             dim3(512), dim3(256), args, 0u, stream);
}

// Round 2
// 4439.593 us; speedup vs baseline: 2.0646x; 2.0646x over previous
//
#include <hip/hip_runtime.h>
#include <hip/hip_cooperative_groups.h>

namespace cg = cooperative_groups;

#define NN    50000
#define RR    4
#define DDEP  5
#define NIN   17400
#define BB    2
#define TT    50
#define EREC  2000000
#define EIN   500000
#define RNN   (RR*NN)   // 200000

struct SP {
  const float* x; const float* rec_w; const float* in_w; const float* bkg;
  const float* v_th; const float* e_l; const float* v_reset; const float* g;
  const float* t_ref; const float* asc_amps; const float* param_k;
  const float* decay; const float* cf; const float* syn_decay; const float* psc_init;
  const float* vscale; const float* voff;
  const int* rec_rows; const int* rec_cols; const int* in_rows; const int* in_cols;
  const int* rest;
  float* out_z; float* out_v;
  float* cur;        // ws: [BB][RNN]  (recurrent scatter target only)
  float* z_hist;     // ws: [BB][DDEP][NN] circular, slot = t % DDEP
  int*   spike_cnt;  // ws: [TT]
  const int* row_ptr;   // ws: [RNN+1] input CSR
  const int* col_s;     // ws: [EIN]
  const float* w_s;     // ws: [EIN]
};

// ---------- CSR build: histogram -> scan -> scatter ----------
__global__ void hist_k(const int* __restrict__ rows, int* __restrict__ cnt) {
  int i = blockIdx.x * blockDim.x + threadIdx.x;
  int n = gridDim.x * blockDim.x;
  for (int e = i; e < EIN; e += n) atomicAdd(&cnt[rows[e]], 1);
}

__global__ __launch_bounds__(1024) void scan_k(const int* __restrict__ cnt,
                                               int* __restrict__ row_ptr,
                                               int* __restrict__ cursor) {
  __shared__ int part[1024];
  const int T = 1024;
  const int CH = (RNN + T - 1) / T;   // 196
  int i = threadIdx.x;
  int base = i * CH;
  int s = 0;
  for (int j = 0; j < CH; ++j) { int idx = base + j; if (idx < RNN) s += cnt[idx]; }
  part[i] = s; __syncthreads();
  for (int off = 1; off < T; off <<= 1) {
    int v = (i >= off) ? part[i - off] : 0;
    __syncthreads();
    part[i] += v;
    __syncthreads();
  }
  int run = part[i] - s;  // exclusive prefix
  for (int j = 0; j < CH; ++j) {
    int idx = base + j;
    if (idx < RNN) { row_ptr[idx] = run; cursor[idx] = run; run += cnt[idx]; }
  }
  if (i == 0) row_ptr[RNN] = EIN;
}

__global__ void scatter_k(const int* __restrict__ rows, const int* __restrict__ cols,
                          const float* __restrict__ w, int* __restrict__ cursor,
                          int* __restrict__ col_s, float* __restrict__ w_s) {
  int i = blockIdx.x * blockDim.x + threadIdx.x;
  int n = gridDim.x * blockDim.x;
  for (int e = i; e < EIN; e += n) {
    int pos = atomicAdd(&cursor[rows[e]], 1);
    col_s[pos] = cols[e];
    w_s[pos]   = w[e];
  }
}

// ---------- main persistent kernel ----------
__global__ __launch_bounds__(256, 2) void snn_all(SP p) {
  cg::grid_group grid = cg::this_grid();
  const int tid = blockIdx.x * blockDim.x + threadIdx.x;
  const int nth = gridDim.x * blockDim.x;

  const bool owner = tid < BB * NN;
  int b = 0, n = 0;
  float sd[RR], pi[RR], bkgv[RR], psc_rise[RR], psc[RR];
  int rbeg[RR], rend[RR];
  float v = 0.f, refr = 0.f, a1 = 0.f, a2 = 0.f, my_z = 0.f;
  float dcy = 0.f, cfac = 0.f, trf = 0.f, amp1 = 0.f, amp2 = 0.f;
  float ad1 = 0.f, ad2 = 0.f, vth = 0.f, invn = 0.f, leak = 0.f;
  float vrst = 0.f, vsc = 0.f, vof = 0.f;
  #pragma unroll
  for (int r = 0; r < RR; ++r) {
    sd[r]=0.f; pi[r]=0.f; bkgv[r]=0.f; psc_rise[r]=0.f; psc[r]=0.f;
    rbeg[r]=0; rend[r]=0;
  }

  if (owner) {
    b = (tid >= NN) ? 1 : 0;
    n = tid - b * NN;
    #pragma unroll
    for (int r = 0; r < RR; ++r) {
      sd[r]   = p.syn_decay[n*RR + r];
      pi[r]   = p.psc_init[n*RR + r];
      bkgv[r] = p.bkg[n*RR + r];
      rbeg[r] = p.row_ptr[n*RR + r];
      rend[r] = p.row_ptr[n*RR + r + 1];
    }
    vth  = p.v_th[n];
    float el = p.e_l[n];
    invn = 1.0f / (vth - el);
    leak = p.g[n] * el;
    vrst = p.v_reset[n];
    v    = vrst;
    dcy  = p.decay[n];
    cfac = p.cf[n];
    trf  = p.t_ref[n];
    amp1 = p.asc_amps[2*n+0];
    amp2 = p.asc_amps[2*n+1];
    ad1  = expf(-p.param_k[2*n+0]);
    ad2  = expf(-p.param_k[2*n+1]);
    vsc  = p.vscale[n];
    vof  = p.voff[n];
  }
  float* curb = p.cur    + (size_t)b * RNN;
  float* zh_b = p.z_hist + (size_t)b * (DDEP * NN);
  const float* xb = p.x + (size_t)b * TT * NIN;
  bool curDirty = false;

  for (int t = 0; t < TT; ++t) {
    grid.sync();   // z_hist / spike_cnt / cur from step t-1 now visible

    // spike window gate (uniform across grid)
    unsigned actmask = 0u;
    #pragma unroll
    for (int d = 0; d < DDEP; ++d) {
      int ts = t - 1 - d;
      if (ts >= 0 && p.spike_cnt[ts] > 0) actmask |= (1u << d);
    }

    if (actmask) {
      // rare path: recurrent scatter from spiking history
      for (int e = tid; e < EREC; e += nth) {
        int col = p.rec_cols[e];           // col = d*NN + n_src
        int d = col / NN;
        if (!((actmask >> d) & 1u)) continue;
        int ts   = t - 1 - d;
        int slot = ts % DDEP;
        int nsrc = col - d * NN;
        float z0 = p.z_hist[slot*NN + nsrc];
        float z1 = p.z_hist[DDEP*NN + slot*NN + nsrc];
        if (z0 == 0.f && z1 == 0.f) continue;
        float w  = p.rec_w[e];
        int row  = p.rec_rows[e];
        if (z0 != 0.f) atomicAdd(&p.cur[row],       w);
        if (z1 != 0.f) atomicAdd(&p.cur[RNN + row], w);
      }
      grid.sync();
      curDirty = true;
    }

    if (owner) {
      float restf = (float)p.rest[t*BB + b] * 0.1f;
      const float* xt = xb + (size_t)t * NIN;
      float rin[RR];
      #pragma unroll
      for (int r = 0; r < RR; ++r) {
        float acc = bkgv[r] * restf;
        for (int e = rbeg[r]; e < rend[r]; ++e)
          acc += xt[p.col_s[e]] * p.w_s[e];
        if (curDirty) {
          acc += curb[n*RR + r];
          curb[n*RR + r] = 0.f;
        }
        rin[r] = acc;
      }
      float prev_z = my_z;
      float input_current = psc[0] + psc[1] + psc[2] + psc[3];   // OLD psc
      float new_v = dcy * v + cfac * (input_current + a1 + a2 + leak)
                    + prev_z * (vrst - vth);
      #pragma unroll
      for (int r = 0; r < RR; ++r) {       // new_psc uses OLD psc_rise
        float npsc = psc[r] * sd[r] + sd[r] * psc_rise[r];
        psc_rise[r] = sd[r] * psc_rise[r] + rin[r] * pi[r];
        psc[r] = npsc;
      }
      refr = fmaxf(refr + prev_z * trf - 1.0f, 0.f);
      a1 = ad1 * a1 + prev_z * amp1;
      a2 = ad2 * a2 + prev_z * amp2;
      v = new_v;
      float v_scaled = (new_v - vth) * invn;
      float z = (v_scaled > 0.f) ? 1.f : 0.f;
      if (refr > 0.f) z = 0.f;
      my_z = z;
      zh_b[(t % DDEP)*NN + n] = z;
      size_t oidx = (size_t)b * (TT*NN) + (size_t)t * NN + n;
      p.out_z[oidx] = z;
      p.out_v[oidx] = new_v * vsc + vof;
      unsigned long long m = __ballot(z != 0.f);
      if ((threadIdx.x & 63) == 0 && m != 0ull)
        atomicAdd(&p.spike_cnt[t], (int)__popcll(m));
    }
    curDirty = false;
  }
}

extern "C" void kernel_launch(void* const* d_in, const int* in_sizes, int n_in,
                              void* d_out, int out_size, void* d_ws, size_t ws_size,
                              hipStream_t stream) {
  SP p;
  p.x        = (const float*)d_in[0];
  p.rec_w    = (const float*)d_in[1];
  p.in_w     = (const float*)d_in[2];
  p.bkg      = (const float*)d_in[3];
  p.v_th     = (const float*)d_in[4];
  p.e_l      = (const float*)d_in[5];
  p.v_reset  = (const float*)d_in[6];
  p.g        = (const float*)d_in[7];
  p.t_ref    = (const float*)d_in[8];
  p.asc_amps = (const float*)d_in[9];
  p.param_k  = (const float*)d_in[10];
  p.decay    = (const float*)d_in[11];
  p.cf       = (const float*)d_in[12];
  p.syn_decay= (const float*)d_in[13];
  p.psc_init = (const float*)d_in[14];
  p.vscale   = (const float*)d_in[15];
  p.voff     = (const float*)d_in[16];
  p.rec_rows = (const int*)d_in[17];
  p.rec_cols = (const int*)d_in[18];
  p.in_rows  = (const int*)d_in[19];
  p.in_cols  = (const int*)d_in[20];
  p.rest     = (const int*)d_in[21];
  p.out_z = (float*)d_out;
  p.out_v = (float*)d_out + (size_t)BB * TT * NN;

  // ---- workspace layout (all 16B aligned) ----
  char* ws = (char*)d_ws;
  size_t off = 0;
  float* cur       = (float*)(ws + off); off += sizeof(float) * (size_t)BB * RNN;      // 1.6 MB
  float* z_hist    = (float*)(ws + off); off += sizeof(float) * (size_t)BB * DDEP * NN; // 2.0 MB
  int*   spike_cnt = (int*)  (ws + off); off += 256;
  int*   cnt       = (int*)  (ws + off); off += sizeof(int) * (size_t)RNN;             // 0.8 MB
  int*   row_ptr   = (int*)  (ws + off); off += ((sizeof(int) * ((size_t)RNN + 1) + 15) & ~(size_t)15);
  int*   cursor    = (int*)  (ws + off); off += sizeof(int) * (size_t)RNN;             // 0.8 MB
  int*   col_s     = (int*)  (ws + off); off += sizeof(int) * (size_t)EIN;             // 2.0 MB
  float* w_s       = (float*)(ws + off); off += sizeof(float) * (size_t)EIN;           // 2.0 MB

  p.cur = cur; p.z_hist = z_hist; p.spike_cnt = spike_cnt;
  p.row_ptr = row_ptr; p.col_s = col_s; p.w_s = w_s;

  hipMemsetAsync(cur, 0, sizeof(float) * (size_t)BB * RNN, stream);
  hipMemsetAsync(spike_cnt, 0, 256, stream);
  hipMemsetAsync(cnt, 0, sizeof(int) * (size_t)RNN, stream);

  hipLaunchKernelGGL(hist_k, dim3(512), dim3(256), 0, stream, p.in_rows, cnt);
  hipLaunchKernelGGL(scan_k, dim3(1), dim3(1024), 0, stream, cnt, row_ptr, cursor);
  hipLaunchKernelGGL(scatter_k, dim3(512), dim3(256), 0, stream,
                     p.in_rows, p.in_cols, p.in_w, cursor, col_s, w_s);

  void* args[] = { (void*)&p };
  hipLaunchCooperativeKernel(reinterpret_cast<const void*>(&snn_all),
                             dim3(400), dim3(256), args, 0u, stream);
}

// Round 3
// 2889.362 us; speedup vs baseline: 3.1723x; 1.5365x over previous
//
#include <hip/hip_runtime.h>
#include <hip/hip_cooperative_groups.h>

namespace cg = cooperative_groups;

#define NN    50000
#define RR    4
#define DDEP  5
#define NIN   17400
#define BB    2
#define TT    50
#define EREC  2000000
#define EIN   500000
#define RNN   (RR*NN)    // 200000
#define DNN   (DDEP*NN)  // 250000
#define RING  6

struct SP {
  const float* x; const float* rec_w; const float* in_w; const float* bkg;
  const float* v_th; const float* e_l; const float* v_reset; const float* g;
  const float* t_ref; const float* asc_amps; const float* param_k;
  const float* decay; const float* cf; const float* syn_decay; const float* psc_init;
  const float* vscale; const float* voff;
  const int* rest;
  float* out_z; float* out_v;
  float* cur_ring;      // ws: [BB][RING][RNN] future-accumulator ring
  const int* row_ptr;   // ws: [RNN+1]  input CSR (by target row)
  const int* col_s;     // ws: [EIN]
  const float* w_s;     // ws: [EIN]
  const int* col_ptr;   // ws: [DNN+1]  rec CSC (by source col = d*NN+src)
  const int* rows_cs;   // ws: [EREC]
  const float* w_cs;    // ws: [EREC]
};

// ---------- generic CSR/CSC build: histogram -> scan -> scatter ----------
__global__ void hist_k(const int* __restrict__ keys, int* __restrict__ cnt, int nE) {
  int i = blockIdx.x * blockDim.x + threadIdx.x;
  int n = gridDim.x * blockDim.x;
  for (int e = i; e < nE; e += n) atomicAdd(&cnt[keys[e]], 1);
}

__global__ __launch_bounds__(1024) void scan_k(const int* __restrict__ cnt,
                                               int* __restrict__ ptr,
                                               int* __restrict__ cursor,
                                               int nRows, int nE) {
  __shared__ int part[1024];
  const int CH = (nRows + 1023) >> 10;
  int i = threadIdx.x;
  int base = i * CH;
  int s = 0;
  for (int j = 0; j < CH; ++j) { int idx = base + j; if (idx < nRows) s += cnt[idx]; }
  part[i] = s; __syncthreads();
  for (int off = 1; off < 1024; off <<= 1) {
    int v = (i >= off) ? part[i - off] : 0;
    __syncthreads();
    part[i] += v;
    __syncthreads();
  }
  int run = part[i] - s;  // exclusive prefix
  for (int j = 0; j < CH; ++j) {
    int idx = base + j;
    if (idx < nRows) { ptr[idx] = run; cursor[idx] = run; run += cnt[idx]; }
  }
  if (i == 0) ptr[nRows] = nE;
}

__global__ void scatter_k(const int* __restrict__ keys, const int* __restrict__ pay_i,
                          const float* __restrict__ pay_f, int* __restrict__ cursor,
                          int* __restrict__ out_i, float* __restrict__ out_f, int nE) {
  int i = blockIdx.x * blockDim.x + threadIdx.x;
  int n = gridDim.x * blockDim.x;
  for (int e = i; e < nE; e += n) {
    int pos = atomicAdd(&cursor[keys[e]], 1);
    out_i[pos] = pay_i[e];
    out_f[pos] = pay_f[e];
  }
}

// ---------- main persistent kernel ----------
__global__ __launch_bounds__(1024, 1) void snn_all(SP p) {
  cg::grid_group grid = cg::this_grid();
  const int tid = blockIdx.x * blockDim.x + threadIdx.x;

  const bool owner = tid < BB * NN;
  int b = 0, n = 0;
  float sd[RR], pi[RR], bkgv[RR], psc_rise[RR], psc[RR];
  int rbeg[RR], rend[RR];
  float v = 0.f, refr = 0.f, a1 = 0.f, a2 = 0.f, my_z = 0.f;
  float dcy = 0.f, cfac = 0.f, trf = 0.f, amp1 = 0.f, amp2 = 0.f;
  float ad1 = 0.f, ad2 = 0.f, vth = 0.f, invn = 0.f, leak = 0.f;
  float vrst = 0.f, vsc = 0.f, vof = 0.f;
  #pragma unroll
  for (int r = 0; r < RR; ++r) {
    sd[r]=0.f; pi[r]=0.f; bkgv[r]=0.f; psc_rise[r]=0.f; psc[r]=0.f;
    rbeg[r]=0; rend[r]=0;
  }

  if (owner) {
    b = (tid >= NN) ? 1 : 0;
    n = tid - b * NN;
    #pragma unroll
    for (int r = 0; r < RR; ++r) {
      sd[r]   = p.syn_decay[n*RR + r];
      pi[r]   = p.psc_init[n*RR + r];
      bkgv[r] = p.bkg[n*RR + r];
      rbeg[r] = p.row_ptr[n*RR + r];
      rend[r] = p.row_ptr[n*RR + r + 1];
    }
    vth  = p.v_th[n];
    float el = p.e_l[n];
    invn = 1.0f / (vth - el);
    leak = p.g[n] * el;
    vrst = p.v_reset[n];
    v    = vrst;
    dcy  = p.decay[n];
    cfac = p.cf[n];
    trf  = p.t_ref[n];
    amp1 = p.asc_amps[2*n+0];
    amp2 = p.asc_amps[2*n+1];
    ad1  = expf(-p.param_k[2*n+0]);
    ad2  = expf(-p.param_k[2*n+1]);
    vsc  = p.vscale[n];
    vof  = p.voff[n];
  }
  const float* xb = p.x + (size_t)b * TT * NIN;
  float* ringB = p.cur_ring + (size_t)b * RING * RNN;

  for (int t = 0; t < TT; ++t) {
    if (t) grid.sync();   // ring writes from step t-1 now visible

    if (owner) {
      float restf = (float)p.rest[t*BB + b] * 0.1f;
      const float* xt = xb + (size_t)t * NIN;

      // recurrent contribution accumulated event-driven into ring slot t%RING
      float4* slotR = (float4*)(ringB + (size_t)(t % RING) * RNN);
      float4 rv = slotR[n];
      slotR[n] = make_float4(0.f, 0.f, 0.f, 0.f);   // reused at step t+RING
      float rin[RR] = { rv.x, rv.y, rv.z, rv.w };

      // input gather (CSR) + background
      #pragma unroll
      for (int r = 0; r < RR; ++r) {
        float acc = bkgv[r] * restf;
        for (int e = rbeg[r]; e < rend[r]; ++e)
          acc += xt[p.col_s[e]] * p.w_s[e];
        rin[r] += acc;
      }

      float prev_z = my_z;
      float input_current = psc[0] + psc[1] + psc[2] + psc[3];   // OLD psc
      float new_v = dcy * v + cfac * (input_current + a1 + a2 + leak)
                    + prev_z * (vrst - vth);
      #pragma unroll
      for (int r = 0; r < RR; ++r) {       // new_psc uses OLD psc_rise
        float npsc = psc[r] * sd[r] + sd[r] * psc_rise[r];
        psc_rise[r] = sd[r] * psc_rise[r] + rin[r] * pi[r];
        psc[r] = npsc;
      }
      refr = fmaxf(refr + prev_z * trf - 1.0f, 0.f);
      a1 = ad1 * a1 + prev_z * amp1;
      a2 = ad2 * a2 + prev_z * amp2;
      v = new_v;
      float v_scaled = (new_v - vth) * invn;
      float z = (v_scaled > 0.f) ? 1.f : 0.f;
      if (refr > 0.f) z = 0.f;
      my_z = z;
      size_t oidx = (size_t)b * (TT*NN) + (size_t)t * NN + n;
      p.out_z[oidx] = z;
      p.out_v[oidx] = new_v * vsc + vof;

      // event-driven scatter: push outgoing edges into future ring slots
      if (z != 0.f) {
        #pragma unroll
        for (int d = 0; d < DDEP; ++d) {
          int col = d * NN + n;
          int be = p.col_ptr[col], en = p.col_ptr[col + 1];
          float* ringW = ringB + (size_t)((t + 1 + d) % RING) * RNN;
          for (int e = be; e < en; ++e)
            atomicAdd(&ringW[p.rows_cs[e]], p.w_cs[e]);
        }
      }
    }
  }
}

extern "C" void kernel_launch(void* const* d_in, const int* in_sizes, int n_in,
                              void* d_out, int out_size, void* d_ws, size_t ws_size,
                              hipStream_t stream) {
  SP p;
  p.x        = (const float*)d_in[0];
  p.rec_w    = (const float*)d_in[1];
  p.in_w     = (const float*)d_in[2];
  p.bkg      = (const float*)d_in[3];
  p.v_th     = (const float*)d_in[4];
  p.e_l      = (const float*)d_in[5];
  p.v_reset  = (const float*)d_in[6];
  p.g        = (const float*)d_in[7];
  p.t_ref    = (const float*)d_in[8];
  p.asc_amps = (const float*)d_in[9];
  p.param_k  = (const float*)d_in[10];
  p.decay    = (const float*)d_in[11];
  p.cf       = (const float*)d_in[12];
  p.syn_decay= (const float*)d_in[13];
  p.psc_init = (const float*)d_in[14];
  p.vscale   = (const float*)d_in[15];
  p.voff     = (const float*)d_in[16];
  const int* rec_rows = (const int*)d_in[17];
  const int* rec_cols = (const int*)d_in[18];
  const int* in_rows  = (const int*)d_in[19];
  const int* in_cols  = (const int*)d_in[20];
  p.rest     = (const int*)d_in[21];
  p.out_z = (float*)d_out;
  p.out_v = (float*)d_out + (size_t)BB * TT * NN;

  // ---- workspace layout (16B aligned blocks) ----
  char* ws = (char*)d_ws;
  size_t off = 0;
  auto alloc = [&](size_t bytes) { void* q = ws + off; off += (bytes + 15) & ~(size_t)15; return q; };
  float* cur_ring = (float*)alloc(sizeof(float) * (size_t)BB * RING * RNN); // 9.6 MB
  int*   row_ptr  = (int*)  alloc(sizeof(int) * ((size_t)RNN + 1));         // 0.8 MB
  int*   col_ptr  = (int*)  alloc(sizeof(int) * ((size_t)DNN + 1));         // 1.0 MB
  int*   cnt      = (int*)  alloc(sizeof(int) * (size_t)DNN);               // 1.0 MB (shared)
  int*   cursor   = (int*)  alloc(sizeof(int) * (size_t)DNN);               // 1.0 MB (shared)
  int*   col_s    = (int*)  alloc(sizeof(int) * (size_t)EIN);               // 2.0 MB
  float* w_s      = (float*)alloc(sizeof(float) * (size_t)EIN);             // 2.0 MB
  int*   rows_cs  = (int*)  alloc(sizeof(int) * (size_t)EREC);              // 8.0 MB
  float* w_cs     = (float*)alloc(sizeof(float) * (size_t)EREC);            // 8.0 MB

  p.cur_ring = cur_ring;
  p.row_ptr = row_ptr; p.col_s = col_s; p.w_s = w_s;
  p.col_ptr = col_ptr; p.rows_cs = rows_cs; p.w_cs = w_cs;

  hipMemsetAsync(cur_ring, 0, sizeof(float) * (size_t)BB * RING * RNN, stream);

  // input CSR (keyed by target row)
  hipMemsetAsync(cnt, 0, sizeof(int) * (size_t)RNN, stream);
  hipLaunchKernelGGL(hist_k, dim3(1024), dim3(256), 0, stream, in_rows, cnt, EIN);
  hipLaunchKernelGGL(scan_k, dim3(1), dim3(1024), 0, stream, cnt, row_ptr, cursor, RNN, EIN);
  hipLaunchKernelGGL(scatter_k, dim3(1024), dim3(256), 0, stream,
                     in_rows, in_cols, p.in_w, cursor, col_s, w_s, EIN);

  // recurrent CSC (keyed by source col = d*NN + src)
  hipMemsetAsync(cnt, 0, sizeof(int) * (size_t)DNN, stream);
  hipLaunchKernelGGL(hist_k, dim3(2048), dim3(256), 0, stream, rec_cols, cnt, EREC);
  hipLaunchKernelGGL(scan_k, dim3(1), dim3(1024), 0, stream, cnt, col_ptr, cursor, DNN, EREC);
  hipLaunchKernelGGL(scatter_k, dim3(2048), dim3(256), 0, stream,
                     rec_cols, rec_rows, p.rec_w, cursor, rows_cs, w_cs, EREC);

  void* args[] = { (void*)&p };
  hipLaunchCooperativeKernel(reinterpret_cast<const void*>(&snn_all),
                             dim3(104), dim3(1024), args, 0u, stream);
}